// Round 6
// baseline (586.884 us; speedup 1.0000x reference)
//
#include <hip/hip_runtime.h>
#include <math.h>

#define N_NODES 4096
#define N_EDGES 131072
#define XPAD    272   // bf16 elems per LDS row

using bf16x8 = __attribute__((ext_vector_type(8))) __bf16;
using f32x4  = __attribute__((ext_vector_type(4))) float;
typedef unsigned short u16;

__device__ __forceinline__ u16 f2bf(float f) {
  union { __bf16 b; u16 u; } cv; cv.b = (__bf16)f; return cv.u;
}
__device__ __forceinline__ float bf2f(u16 h) {
  return __uint_as_float(((unsigned)h) << 16);
}
__device__ __forceinline__ float gelu_tanh(float x) {
  float t = x * x;
  float y = x * (1.5957691216057308f + 0.07135481627f * t);
  float e = __expf(y);
  return x - x / (1.0f + e);
}
__device__ __forceinline__ f32x4 mfma16(bf16x8 a, bf16x8 b, f32x4 c) {
  return __builtin_amdgcn_mfma_f32_16x16x32_bf16(a, b, c, 0, 0, 0);
}
__device__ __forceinline__ bf16x8 cat8(ushort4 a, ushort4 b) {
  union { bf16x8 v; ushort4 u[2]; } x; x.u[0] = a; x.u[1] = b; return x.v;
}

struct WPtrs { const float* p[10]; };

// ---------------- setup: pack weights (coalesced) + hist + qkv bias -------------
__global__ void setup_kernel(WPtrs w, u16* __restrict__ dst, float qscale,
                             const int* __restrict__ ei, int* __restrict__ deg,
                             const float* __restrict__ bq, const float* __restrict__ bk,
                             const float* __restrict__ bv, float* __restrict__ qkvbias) {
  int blk = blockIdx.x, t = threadIdx.x;
  if (blk < 512) {
    int tid = blk * 256 + t;
    int m, ci;
    if (tid < 32768)      { m = tid >> 13;                 ci = tid & 8191; }
    else if (tid < 57344) { m = 4 + ((tid - 32768) >> 13); ci = (tid - 32768) & 8191; }
    else if (tid < 65536) { m = 7; ci = tid - 57344; }
    else if (tid < 98304) { m = 8; ci = tid - 65536; }
    else                  { m = 9; ci = tid - 98304; }
    int Cols = (m == 8) ? 1024 : 256;
    int k8   = (m == 8) ? (ci >> 10) : (ci >> 8);
    int c    = (m == 8) ? (ci & 1023) : (ci & 255);
    const float* src = w.p[m] + (size_t)(k8 * 8) * Cols + c;
    float sc = (m == 4) ? qscale : 1.0f;
    u16 tmp[8];
#pragma unroll
    for (int j = 0; j < 8; ++j) tmp[j] = f2bf(src[(size_t)j * Cols] * sc);
    size_t off;
    if (m < 4)       off = (size_t)(m << 16) + (size_t)(k8 * 256 + c) * 8;
    else if (m < 7)  off = 262144 + (size_t)(k8 * 768 + (m - 4) * 256 + c) * 8;
    else if (m == 7) off = 458752 + (size_t)(k8 * 256 + c) * 8;
    else if (m == 8) off = 524288 + (size_t)(k8 * 1024 + c) * 8;
    else             off = 786432 + (size_t)(k8 * 256 + c) * 8;
    *(uint4*)(dst + off) = *(const uint4*)tmp;
  } else if (blk < 1024) {
    int e = (blk - 512) * 256 + t;
    atomicAdd(&deg[ei[N_EDGES + e]], 1);
  } else {
#pragma unroll
    for (int i = 0; i < 3; ++i) {
      int idx = i * 256 + t;
      qkvbias[idx] = idx < 256 ? bq[idx] * qscale : (idx < 512 ? bk[idx - 256] : bv[idx - 512]);
    }
  }
}

// ---------------- scan ----------------------------------------------------------
__global__ void scan_kernel(const int* __restrict__ deg, int* __restrict__ offs) {
  __shared__ int part[1024];
  int t = threadIdx.x;
  int base = t * 4;
  int a0 = deg[base], a1 = deg[base + 1], a2 = deg[base + 2], a3 = deg[base + 3];
  int s = a0 + a1 + a2 + a3;
  part[t] = s;
  __syncthreads();
  for (int off = 1; off < 1024; off <<= 1) {
    int v = (t >= off) ? part[t - off] : 0;
    __syncthreads();
    part[t] += v;
    __syncthreads();
  }
  int excl = part[t] - s;
  offs[base] = excl;
  offs[base + 1] = excl + a0;
  offs[base + 2] = excl + a0 + a1;
  offs[base + 3] = excl + a0 + a1 + a2;
  if (t == 1023) offs[4096] = part[1023];
}

// ---------------- mid: scatter + LN_local ---------------------------------------
__global__ void mid_kernel(const int* __restrict__ ei, const int* __restrict__ offs,
                           int* __restrict__ cnt, int* __restrict__ eperm,
                           int* __restrict__ dst_s, int* __restrict__ src_s,
                           const float* __restrict__ x, const float* __restrict__ g,
                           const float* __restrict__ b, float* __restrict__ hf,
                           u16* __restrict__ hb) {
  int blk = blockIdx.x, t = threadIdx.x;
  if (blk < 512) {
    int e = blk * 256 + t;
    int d = ei[N_EDGES + e];
    int p = offs[d] + atomicAdd(&cnt[d], 1);
    eperm[p] = e;
    dst_s[p] = d;
    src_s[p] = ei[e];
  } else {
    int row = blk - 512;
    float v = x[(size_t)row * 256 + t];
    float s1 = v, s2 = v * v;
#pragma unroll
    for (int o = 32; o > 0; o >>= 1) { s1 += __shfl_xor(s1, o); s2 += __shfl_xor(s2, o); }
    __shared__ float a1[4], a2[4];
    int wv = t >> 6, lane = t & 63;
    if (lane == 0) { a1[wv] = s1; a2[wv] = s2; }
    __syncthreads();
    s1 = a1[0] + a1[1] + a1[2] + a1[3];
    s2 = a2[0] + a2[1] + a2[2] + a2[3];
    float mean = s1 * (1.0f / 256.0f);
    float var  = s2 * (1.0f / 256.0f) - mean * mean;
    float rs = rsqrtf(var + 1e-5f);
    float o = (v - mean) * rs * g[t] + b[t];
    hf[(size_t)row * 256 + t] = o;
    hb[(size_t)row * 256 + t] = f2bf(o);
  }
}

// ---------------- fused edge MLP + in-block segment sum -------------------------
__launch_bounds__(256, 2)
__global__ void edge_kernel(const u16* __restrict__ hb, const float* __restrict__ ea,
                            const int* __restrict__ eperm, const int* __restrict__ src_s,
                            const int* __restrict__ dst_s,
                            const u16* __restrict__ wp1, const float* __restrict__ b1,
                            const u16* __restrict__ wp2, const float* __restrict__ b2,
                            float* __restrict__ agg) {
  __shared__ __align__(16) u16 X[128 * XPAD];
  const f32x4 fzero = {0.f, 0.f, 0.f, 0.f};
  int t = threadIdx.x;
  int lane = t & 63, wv = t >> 6;
  int lr = lane & 15, lq = lane >> 4;
  int e0 = blockIdx.x * 128;
  int col0 = wv * 64;

  const u16* b1ptr = wp1 + ((size_t)lq * 256 + col0 + lr) * 8;
  const u16* b2ptr = wp2 + ((size_t)lq * 256 + col0 + lr) * 8;
  bf16x8 bc[4], bn[4];
#pragma unroll
  for (int ct = 0; ct < 4; ++ct) bc[ct] = *(const bf16x8*)(b1ptr + ct * 128);

  int ci = (t & 31) * 8;
#pragma unroll
  for (int it = 0; it < 16; ++it) {
    int r = it * 8 + (t >> 5);
    int e = eperm[e0 + r];
    int s = src_s[e0 + r];
    const float* pa = ea + (size_t)e * 256 + ci;
    float4 a0 = *(const float4*)pa;
    float4 a1 = *(const float4*)(pa + 4);
    ushort4 h0 = *(const ushort4*)(hb + (size_t)s * 256 + ci);
    ushort4 h1 = *(const ushort4*)(hb + (size_t)s * 256 + ci + 4);
    u16 tmp[8];
    tmp[0] = f2bf(a0.x + bf2f(h0.x)); tmp[1] = f2bf(a0.y + bf2f(h0.y));
    tmp[2] = f2bf(a0.z + bf2f(h0.z)); tmp[3] = f2bf(a0.w + bf2f(h0.w));
    tmp[4] = f2bf(a1.x + bf2f(h1.x)); tmp[5] = f2bf(a1.y + bf2f(h1.y));
    tmp[6] = f2bf(a1.z + bf2f(h1.z)); tmp[7] = f2bf(a1.w + bf2f(h1.w));
    *(uint4*)&X[r * XPAD + ci] = *(const uint4*)tmp;
  }
  __syncthreads();

  f32x4 acc[8][4];
#pragma unroll
  for (int i = 0; i < 8; ++i)
#pragma unroll
    for (int j = 0; j < 4; ++j) acc[i][j] = fzero;

#pragma unroll
  for (int ks = 0; ks < 8; ++ks) {
    if (ks < 7) {
#pragma unroll
      for (int ct = 0; ct < 4; ++ct)
        bn[ct] = *(const bf16x8*)(b1ptr + (size_t)(ks + 1) * 8192 + ct * 128);
    }
    bf16x8 a[4];
#pragma unroll
    for (int rt = 0; rt < 4; ++rt)
      a[rt] = *(const bf16x8*)&X[(rt * 16 + lr) * XPAD + ks * 32 + lq * 8];
#pragma unroll
    for (int ct = 0; ct < 4; ++ct)
#pragma unroll
      for (int rt = 0; rt < 4; ++rt) acc[rt][ct] = mfma16(a[rt], bc[ct], acc[rt][ct]);
#pragma unroll
    for (int rt = 0; rt < 4; ++rt)
      a[rt] = *(const bf16x8*)&X[((rt + 4) * 16 + lr) * XPAD + ks * 32 + lq * 8];
#pragma unroll
    for (int ct = 0; ct < 4; ++ct)
#pragma unroll
      for (int rt = 0; rt < 4; ++rt) acc[rt + 4][ct] = mfma16(a[rt], bc[ct], acc[rt + 4][ct]);
#pragma unroll
    for (int ct = 0; ct < 4; ++ct) bc[ct] = bn[ct];
  }
#pragma unroll
  for (int ct = 0; ct < 4; ++ct) bn[ct] = *(const bf16x8*)(b2ptr + ct * 128);
  __syncthreads();

#pragma unroll
  for (int ct = 0; ct < 4; ++ct) {
    int c = col0 + ct * 16 + lr;
    float bb = b1[c];
#pragma unroll
    for (int rt = 0; rt < 8; ++rt)
#pragma unroll
      for (int r = 0; r < 4; ++r) {
        int row = rt * 16 + lq * 4 + r;
        X[row * XPAD + c] = f2bf(gelu_tanh(acc[rt][ct][r] + bb));
      }
  }
#pragma unroll
  for (int ct = 0; ct < 4; ++ct) bc[ct] = bn[ct];
  __syncthreads();

#pragma unroll
  for (int i = 0; i < 8; ++i)
#pragma unroll
    for (int j = 0; j < 4; ++j) acc[i][j] = fzero;
#pragma unroll
  for (int ks = 0; ks < 8; ++ks) {
    if (ks < 7) {
#pragma unroll
      for (int ct = 0; ct < 4; ++ct)
        bn[ct] = *(const bf16x8*)(b2ptr + (size_t)(ks + 1) * 8192 + ct * 128);
    }
    bf16x8 a[4];
#pragma unroll
    for (int rt = 0; rt < 4; ++rt)
      a[rt] = *(const bf16x8*)&X[(rt * 16 + lr) * XPAD + ks * 32 + lq * 8];
#pragma unroll
    for (int ct = 0; ct < 4; ++ct)
#pragma unroll
      for (int rt = 0; rt < 4; ++rt) acc[rt][ct] = mfma16(a[rt], bc[ct], acc[rt][ct]);
#pragma unroll
    for (int rt = 0; rt < 4; ++rt)
      a[rt] = *(const bf16x8*)&X[((rt + 4) * 16 + lr) * XPAD + ks * 32 + lq * 8];
#pragma unroll
    for (int ct = 0; ct < 4; ++ct)
#pragma unroll
      for (int rt = 0; rt < 4; ++rt) acc[rt + 4][ct] = mfma16(a[rt], bc[ct], acc[rt + 4][ct]);
#pragma unroll
    for (int ct = 0; ct < 4; ++ct) bc[ct] = bn[ct];
  }
  __syncthreads();

#pragma unroll
  for (int ct = 0; ct < 4; ++ct) {
    int c = col0 + ct * 16 + lr;
    float bb = b2[c];
#pragma unroll
    for (int rt = 0; rt < 8; ++rt)
#pragma unroll
      for (int r = 0; r < 4; ++r) {
        int row = rt * 16 + lq * 4 + r;
        X[row * XPAD + c] = f2bf(acc[rt][ct][r] + bb);
      }
  }
  __syncthreads();

  {
    int c4 = lane * 4;
    int rbeg = wv * 32;
    float run0 = 0.f, run1 = 0.f, run2 = 0.f, run3 = 0.f;
    int cur = dst_s[e0 + rbeg];
    for (int r = rbeg; r < rbeg + 32; ++r) {
      int d = dst_s[e0 + r];
      if (d != cur) {
        float* p = &agg[(size_t)cur * 256 + c4];
        atomicAdd(p + 0, run0); atomicAdd(p + 1, run1);
        atomicAdd(p + 2, run2); atomicAdd(p + 3, run3);
        run0 = run1 = run2 = run3 = 0.f;
        cur = d;
      }
      ushort4 xv = *(const ushort4*)&X[r * XPAD + c4];
      run0 += bf2f(xv.x); run1 += bf2f(xv.y); run2 += bf2f(xv.z); run3 += bf2f(xv.w);
    }
    float* p = &agg[(size_t)cur * 256 + c4];
    atomicAdd(p + 0, run0); atomicAdd(p + 1, run1);
    atomicAdd(p + 2, run2); atomicAdd(p + 3, run3);
  }
}

// ---------------- fused node-update MLP + residual + LN_global (32-row tiles) ---
__launch_bounds__(256, 2)
__global__ void update_kernel(const float* __restrict__ hf, const float* __restrict__ agg,
                              const float* __restrict__ epsp, const float* __restrict__ xin,
                              const u16* __restrict__ wp1, const float* __restrict__ b1,
                              const u16* __restrict__ wp2, const float* __restrict__ b2,
                              const float* __restrict__ lng, const float* __restrict__ lnb,
                              float* __restrict__ x1, u16* __restrict__ gb) {
  __shared__ __align__(16) u16 X[32 * XPAD];
  __shared__ float S1[32][4], S2[32][4], MUs[32], RSs[32];
  const f32x4 fzero = {0.f, 0.f, 0.f, 0.f};
  int t = threadIdx.x;
  int lane = t & 63, wv = t >> 6;
  int lr = lane & 15, lq = lane >> 4;
  int n0 = blockIdx.x * 32;
  int col0 = wv * 64;
  float epv = 1.0f + epsp[0];
  const u16* b1ptr = wp1 + ((size_t)lq * 256 + col0 + lr) * 8;
  const u16* b2ptr = wp2 + ((size_t)lq * 256 + col0 + lr) * 8;
  bf16x8 bc[4], bn[4];
#pragma unroll
  for (int ct = 0; ct < 4; ++ct) bc[ct] = *(const bf16x8*)(b1ptr + ct * 128);
  {
    int c4 = (t & 63) * 4;
#pragma unroll
    for (int ii = 0; ii < 8; ++ii) {
      int r = ii * 4 + wv;
      float4 h = *(const float4*)(hf + (size_t)(n0 + r) * 256 + c4);
      float4 a = *(const float4*)(agg + (size_t)(n0 + r) * 256 + c4);
      *(ushort4*)&X[r * XPAD + c4] =
          make_ushort4(f2bf(epv * h.x + a.x), f2bf(epv * h.y + a.y),
                       f2bf(epv * h.z + a.z), f2bf(epv * h.w + a.w));
    }
  }
  __syncthreads();
  f32x4 acc[2][4];
#pragma unroll
  for (int i = 0; i < 2; ++i)
#pragma unroll
    for (int j = 0; j < 4; ++j) acc[i][j] = fzero;
#pragma unroll
  for (int ks = 0; ks < 8; ++ks) {
    if (ks < 7) {
#pragma unroll
      for (int ct = 0; ct < 4; ++ct)
        bn[ct] = *(const bf16x8*)(b1ptr + (size_t)(ks + 1) * 8192 + ct * 128);
    }
    bf16x8 a[2];
#pragma unroll
    for (int rt = 0; rt < 2; ++rt)
      a[rt] = *(const bf16x8*)&X[(rt * 16 + lr) * XPAD + ks * 32 + lq * 8];
#pragma unroll
    for (int ct = 0; ct < 4; ++ct)
#pragma unroll
      for (int rt = 0; rt < 2; ++rt) acc[rt][ct] = mfma16(a[rt], bc[ct], acc[rt][ct]);
#pragma unroll
    for (int ct = 0; ct < 4; ++ct) bc[ct] = bn[ct];
  }
#pragma unroll
  for (int ct = 0; ct < 4; ++ct) bn[ct] = *(const bf16x8*)(b2ptr + ct * 128);
  __syncthreads();
#pragma unroll
  for (int ct = 0; ct < 4; ++ct) {
    int c = col0 + ct * 16 + lr;
    float bb = b1[c];
#pragma unroll
    for (int rt = 0; rt < 2; ++rt)
#pragma unroll
      for (int r = 0; r < 4; ++r) {
        int row = rt * 16 + lq * 4 + r;
        X[row * XPAD + c] = f2bf(gelu_tanh(acc[rt][ct][r] + bb));
      }
  }
#pragma unroll
  for (int ct = 0; ct < 4; ++ct) bc[ct] = bn[ct];
  __syncthreads();
#pragma unroll
  for (int i = 0; i < 2; ++i)
#pragma unroll
    for (int j = 0; j < 4; ++j) acc[i][j] = fzero;
#pragma unroll
  for (int ks = 0; ks < 8; ++ks) {
    if (ks < 7) {
#pragma unroll
      for (int ct = 0; ct < 4; ++ct)
        bn[ct] = *(const bf16x8*)(b2ptr + (size_t)(ks + 1) * 8192 + ct * 128);
    }
    bf16x8 a[2];
#pragma unroll
    for (int rt = 0; rt < 2; ++rt)
      a[rt] = *(const bf16x8*)&X[(rt * 16 + lr) * XPAD + ks * 32 + lq * 8];
#pragma unroll
    for (int ct = 0; ct < 4; ++ct)
#pragma unroll
      for (int rt = 0; rt < 2; ++rt) acc[rt][ct] = mfma16(a[rt], bc[ct], acc[rt][ct]);
#pragma unroll
    for (int ct = 0; ct < 4; ++ct) bc[ct] = bn[ct];
  }
  float bb2[4];
#pragma unroll
  for (int ct = 0; ct < 4; ++ct) bb2[ct] = b2[col0 + ct * 16 + lr];
#pragma unroll
  for (int rt = 0; rt < 2; ++rt)
#pragma unroll
    for (int r = 0; r < 4; ++r) {
      int row = rt * 16 + lq * 4 + r;
      int grow = n0 + row;
      float p1 = 0.f, p2 = 0.f;
#pragma unroll
      for (int ct = 0; ct < 4; ++ct) {
        int c = col0 + ct * 16 + lr;
        float v = acc[rt][ct][r] + bb2[ct] + xin[(size_t)grow * 256 + c];
        x1[(size_t)grow * 256 + c] = v;
        acc[rt][ct][r] = v;
        p1 += v; p2 += v * v;
      }
#pragma unroll
      for (int o = 1; o < 16; o <<= 1) { p1 += __shfl_xor(p1, o); p2 += __shfl_xor(p2, o); }
      if (lr == 0) { S1[row][wv] = p1; S2[row][wv] = p2; }
    }
  __syncthreads();
  if (t < 32) {
    float s1 = S1[t][0] + S1[t][1] + S1[t][2] + S1[t][3];
    float s2 = S2[t][0] + S2[t][1] + S2[t][2] + S2[t][3];
    float mu = s1 * (1.0f / 256.0f);
    float var = s2 * (1.0f / 256.0f) - mu * mu;
    MUs[t] = mu;
    RSs[t] = rsqrtf(var + 1e-5f);
  }
  __syncthreads();
  float gv[4], bv[4];
#pragma unroll
  for (int ct = 0; ct < 4; ++ct) {
    int c = col0 + ct * 16 + lr;
    gv[ct] = lng[c]; bv[ct] = lnb[c];
  }
#pragma unroll
  for (int rt = 0; rt < 2; ++rt)
#pragma unroll
    for (int r = 0; r < 4; ++r) {
      int row = rt * 16 + lq * 4 + r;
      int grow = n0 + row;
      float mu = MUs[row], rs = RSs[row];
#pragma unroll
      for (int ct = 0; ct < 4; ++ct) {
        int c = col0 + ct * 16 + lr;
        gb[(size_t)grow * 256 + c] = f2bf((acc[rt][ct][r] - mu) * rs * gv[ct] + bv[ct]);
      }
    }
}

// ---------------- generic GEMM (+opt GELU / residual / fused-LN / QKV split) ----
template <int ROWS, bool GELU_F, bool RES, bool OUTB, bool LNF, bool QKV>
__launch_bounds__(256, 2)
__global__ void gemm_kernel(const u16* __restrict__ A, int lda,
                            const u16* __restrict__ Wp, int K, int WCols,
                            const float* __restrict__ bias, float scale,
                            const float* __restrict__ res,
                            const float* __restrict__ lng, const float* __restrict__ lnb,
                            float* __restrict__ outf, u16* __restrict__ outh,
                            u16* __restrict__ outh2, u16* __restrict__ vtp, int ldo) {
  __shared__ __align__(16) u16 X[ROWS * XPAD];
  __shared__ float S1[LNF ? ROWS : 1][4], S2[LNF ? ROWS : 1][4];
  __shared__ float MUs[LNF ? ROWS : 1], RSs[LNF ? ROWS : 1];
  constexpr int RT = ROWS / 16;
  const f32x4 fzero = {0.f, 0.f, 0.f, 0.f};
  int t = threadIdx.x;
  int lane = t & 63, wv = t >> 6;
  int lr = lane & 15, lq = lane >> 4;
  int r0 = blockIdx.x * ROWS;
  int cb = blockIdx.y * 256;
  f32x4 acc[RT][4];
#pragma unroll
  for (int i = 0; i < RT; ++i)
#pragma unroll
    for (int j = 0; j < 4; ++j) acc[i][j] = fzero;
  const u16* bptr = Wp + ((size_t)lq * WCols + cb + wv * 64 + lr) * 8;
  bf16x8 bc[4], bn[4];
#pragma unroll
  for (int ct = 0; ct < 4; ++ct) bc[ct] = *(const bf16x8*)(bptr + ct * 128);
  int rr = t >> 5, c8 = (t & 31) * 8;
  for (int kc = 0; kc < K; kc += 256) {
#pragma unroll
    for (int ii = 0; ii < ROWS / 8; ++ii) {
      int r = ii * 8 + rr;
      *(uint4*)&X[r * XPAD + c8] = *(const uint4*)(A + (size_t)(r0 + r) * lda + kc + c8);
    }
    __syncthreads();
#pragma unroll
    for (int ks = 0; ks < 8; ++ks) {
      bool more = (ks < 7) || (kc + 256 < K);
      if (more) {
        size_t koff = (ks < 7) ? ((size_t)(kc >> 3) + (ks + 1) * 4) * WCols
                               : ((size_t)((kc + 256) >> 3)) * WCols;
#pragma unroll
        for (int ct = 0; ct < 4; ++ct)
          bn[ct] = *(const bf16x8*)(bptr + (koff + ct * 16) * 8);
      }
      bf16x8 a[RT];
#pragma unroll
      for (int rt = 0; rt < RT; ++rt)
        a[rt] = *(const bf16x8*)&X[(rt * 16 + lr) * XPAD + ks * 32 + lq * 8];
#pragma unroll
      for (int ct = 0; ct < 4; ++ct)
#pragma unroll
        for (int rt = 0; rt < RT; ++rt) acc[rt][ct] = mfma16(a[rt], bc[ct], acc[rt][ct]);
#pragma unroll
      for (int ct = 0; ct < 4; ++ct) bc[ct] = bn[ct];
    }
    __syncthreads();
  }
  if (QKV) {
    int y = blockIdx.y;
#pragma unroll
    for (int ct = 0; ct < 4; ++ct) {
      int c = cb + wv * 64 + ct * 16 + lr;
      float bb = bias[c];
#pragma unroll
      for (int rt = 0; rt < RT; ++rt)
#pragma unroll
        for (int r = 0; r < 4; ++r) {
          int row = r0 + rt * 16 + lq * 4 + r;
          u16 hv = f2bf(acc[rt][ct][r] + bb);
          if (y == 0)      outh[(size_t)row * 256 + c] = hv;
          else if (y == 1) outh2[(size_t)row * 256 + (c - 256)] = hv;
          else             vtp[(size_t)(c - 512) * 4096 + row] = hv;
        }
    }
  } else if (!LNF) {
#pragma unroll
    for (int ct = 0; ct < 4; ++ct) {
      int c = cb + wv * 64 + ct * 16 + lr;
      float bb = bias[c];
#pragma unroll
      for (int rt = 0; rt < RT; ++rt)
#pragma unroll
        for (int r = 0; r < 4; ++r) {
          int row = r0 + rt * 16 + lq * 4 + r;
          float v = (acc[rt][ct][r] + bb) * scale;
          if (GELU_F) v = gelu_tanh(v);
          if (RES) v += res[(size_t)row * 256 + c];
          if (OUTB) outh[(size_t)row * ldo + c] = f2bf(v);
          else      outf[(size_t)row * ldo + c] = v;
        }
    }
  } else {
    float bb[4];
#pragma unroll
    for (int ct = 0; ct < 4; ++ct) bb[ct] = bias[wv * 64 + ct * 16 + lr];
#pragma unroll
    for (int rt = 0; rt < RT; ++rt)
#pragma unroll
      for (int r = 0; r < 4; ++r) {
        int row = rt * 16 + lq * 4 + r;
        int grow = r0 + row;
        float p1 = 0.f, p2 = 0.f;
#pragma unroll
        for (int ct = 0; ct < 4; ++ct) {
          int c = wv * 64 + ct * 16 + lr;
          float v = acc[rt][ct][r] + bb[ct];
          if (RES) v += res[(size_t)grow * 256 + c];
          outf[(size_t)grow * 256 + c] = v;
          acc[rt][ct][r] = v;
          p1 += v; p2 += v * v;
        }
#pragma unroll
        for (int o = 1; o < 16; o <<= 1) { p1 += __shfl_xor(p1, o); p2 += __shfl_xor(p2, o); }
        if (lr == 0) { S1[row][wv] = p1; S2[row][wv] = p2; }
      }
    __syncthreads();
    if (t < ROWS) {
      float s1 = S1[t][0] + S1[t][1] + S1[t][2] + S1[t][3];
      float s2 = S2[t][0] + S2[t][1] + S2[t][2] + S2[t][3];
      float mu = s1 * (1.0f / 256.0f);
      float var = s2 * (1.0f / 256.0f) - mu * mu;
      MUs[t] = mu;
      RSs[t] = rsqrtf(var + 1e-5f);
    }
    __syncthreads();
    float gv[4], bv[4];
#pragma unroll
    for (int ct = 0; ct < 4; ++ct) {
      int c = wv * 64 + ct * 16 + lr;
      gv[ct] = lng[c]; bv[ct] = lnb[c];
    }
#pragma unroll
    for (int rt = 0; rt < RT; ++rt)
#pragma unroll
      for (int r = 0; r < 4; ++r) {
        int row = rt * 16 + lq * 4 + r;
        int grow = r0 + row;
        float mu = MUs[row], rs = RSs[row];
#pragma unroll
        for (int ct = 0; ct < 4; ++ct) {
          int c = wv * 64 + ct * 16 + lr;
          outh[(size_t)grow * ldo + c] = f2bf((acc[rt][ct][r] - mu) * rs * gv[ct] + bv[ct]);
        }
      }
  }
}

// ---------------- flash attention: LDS-free K-loop --------------------------------
// S^T = mfma(A=K, B=Q) lands scores in exactly the A-fragment layout needed for
// PV (k-order permuted; V B-frags loaded from vT in the same order). No LDS, no
// barriers, no shuffles in the loop. Key-split x2 across wave pairs; merge via a
// small LDS epilogue (valid because no-max softmax partial sums are additive).
__launch_bounds__(256, 4)
__global__ void attn_kernel(const u16* __restrict__ qb, const u16* __restrict__ kb,
                            const u16* __restrict__ vT, u16* __restrict__ ctx) {
  __shared__ float Osh[4][16 * 36];   // [wave][q*36 + d]
  __shared__ float Lsh[4][16];
  const f32x4 fzero = {0.f, 0.f, 0.f, 0.f};
  int t = threadIdx.x;
  int lane = t & 63, wv = t >> 6;
  int lr = lane & 15, lq = lane >> 4;
  int head = blockIdx.y;
  int qt = wv >> 1;           // q-tile within block (2 per block)
  int kh = wv & 1;            // key half
  int q0 = blockIdx.x * 32 + qt * 16;
  // Q as B-operand: lane holds q = lr, d = lq*8+[0,8)
  bf16x8 qf = *(const bf16x8*)(qb + (size_t)(q0 + lr) * 256 + head * 32 + lq * 8);
  const u16* v0base = vT + (size_t)(head * 32 + lr) * 4096;        // d = lr
  const u16* v1base = vT + (size_t)(head * 32 + 16 + lr) * 4096;   // d = lr+16
  f32x4 o0 = fzero, o1 = fzero;
  float lsum = 0.f;
  for (int k0 = kh * 2048; k0 < kh * 2048 + 2048; k0 += 64) {
    bf16x8 kf[4];
#pragma unroll
    for (int ct = 0; ct < 4; ++ct)
      kf[ct] = *(const bf16x8*)(kb + (size_t)(k0 + ct * 16 + lr) * 256 + head * 32 + lq * 8);
    ushort4 v00a = *(const ushort4*)(v0base + k0 + lq * 4);
    ushort4 v00b = *(const ushort4*)(v0base + k0 + 16 + lq * 4);
    ushort4 v01a = *(const ushort4*)(v0base + k0 + 32 + lq * 4);
    ushort4 v01b = *(const ushort4*)(v0base + k0 + 48 + lq * 4);
    ushort4 v10a = *(const ushort4*)(v1base + k0 + lq * 4);
    ushort4 v10b = *(const ushort4*)(v1base + k0 + 16 + lq * 4);
    ushort4 v11a = *(const ushort4*)(v1base + k0 + 32 + lq * 4);
    ushort4 v11b = *(const ushort4*)(v1base + k0 + 48 + lq * 4);
    f32x4 s[4];
#pragma unroll
    for (int ct = 0; ct < 4; ++ct) s[ct] = mfma16(kf[ct], qf, fzero);
#pragma unroll
    for (int ct = 0; ct < 4; ++ct)
#pragma unroll
      for (int r = 0; r < 4; ++r) { s[ct][r] = __expf(s[ct][r]); lsum += s[ct][r]; }
    bf16x8 p0, p1;
#pragma unroll
    for (int r = 0; r < 4; ++r) {
      p0[r] = (__bf16)s[0][r]; p0[r + 4] = (__bf16)s[1][r];
      p1[r] = (__bf16)s[2][r]; p1[r + 4] = (__bf16)s[3][r];
    }
    o0 = mfma16(p0, cat8(v00a, v00b), o0);
    o0 = mfma16(p1, cat8(v01a, v01b), o0);
    o1 = mfma16(p0, cat8(v10a, v10b), o1);
    o1 = mfma16(p1, cat8(v11a, v11b), o1);
  }
  // reduce l over quads (lanes sharing q = lr)
  lsum += __shfl_xor(lsum, 16);
  lsum += __shfl_xor(lsum, 32);
  if (lq == 0) Lsh[wv][lr] = lsum;
  // O: lane holds (q = lq*4+r, d = lr / lr+16)
#pragma unroll
  for (int r = 0; r < 4; ++r) {
    Osh[wv][(lq * 4 + r) * 36 + lr] = o0[r];
    Osh[wv][(lq * 4 + r) * 36 + 16 + lr] = o1[r];
  }
  __syncthreads();
  // combine key-halves and write ctx: 2 qtiles x 16 q x 32 d
  int qt2 = t >> 7, qq = (t >> 3) & 15, d4 = (t & 7) * 4;
  f32x4 oa = *(const f32x4*)&Osh[qt2 * 2][qq * 36 + d4];
  f32x4 ob = *(const f32x4*)&Osh[qt2 * 2 + 1][qq * 36 + d4];
  float inv = 1.0f / (Lsh[qt2 * 2][qq] + Lsh[qt2 * 2 + 1][qq]);
  ushort4 outv = make_ushort4(f2bf((oa[0] + ob[0]) * inv), f2bf((oa[1] + ob[1]) * inv),
                              f2bf((oa[2] + ob[2]) * inv), f2bf((oa[3] + ob[3]) * inv));
  *(ushort4*)(ctx + (size_t)(blockIdx.x * 32 + qt2 * 16 + qq) * 256 + head * 32 + d4) = outv;
}

// ---------------- host launch ---------------------------------------------------
extern "C" void kernel_launch(void* const* d_in, const int* in_sizes, int n_in,
                              void* d_out, int out_size, void* d_ws, size_t ws_size,
                              hipStream_t stream) {
  const float* x         = (const float*)d_in[0];
  const int*   ei        = (const int*)d_in[1];
  const float* edge_attr = (const float*)d_in[2];
  const float* eps       = (const float*)d_in[3];
  const float* e_w1 = (const float*)d_in[4];
  const float* e_b1 = (const float*)d_in[5];
  const float* e_w2 = (const float*)d_in[6];
  const float* e_b2 = (const float*)d_in[7];
  const float* u_w1 = (const float*)d_in[8];
  const float* u_b1 = (const float*)d_in[9];
  const float* u_w2 = (const float*)d_in[10];
  const float* u_b2 = (const float*)d_in[11];
  const float* ln_local_g  = (const float*)d_in[12];
  const float* ln_local_b  = (const float*)d_in[13];
  const float* ln_global_g = (const float*)d_in[14];
  const float* ln_global_b = (const float*)d_in[15];
  const float* ln_ffn_g    = (const float*)d_in[16];
  const float* ln_ffn_b    = (const float*)d_in[17];
  const float* wq = (const float*)d_in[18];
  const float* wk = (const float*)d_in[19];
  const float* wv = (const float*)d_in[20];
  const float* bq = (const float*)d_in[21];
  const float* bk = (const float*)d_in[22];
  const float* bv = (const float*)d_in[23];
  const float* wo = (const float*)d_in[24];
  const float* bo = (const float*)d_in[25];
  const float* f_w1 = (const float*)d_in[26];
  const float* f_b1 = (const float*)d_in[27];
  const float* f_w2 = (const float*)d_in[28];
  const float* f_b2 = (const float*)d_in[29];

  char* ws = (char*)d_ws;
  u16*   WP      = (u16*)(ws + 0);                         // 2 MB
  float* agg     = (float*)(ws + (2u  << 20));             // 4 MB
  int*   deg     = (int*)(ws + (6u  << 20));               // 16 KB
  int*   cnt     = (int*)(ws + (6u  << 20) + (16u << 10)); // 16 KB
  int*   offs    = (int*)(ws + (6u  << 20) + (32u << 10)); // 16.4 KB
  float* qkvbias = (float*)(ws + (6u << 20) + (64u << 10));// 3 KB
  float* hf      = (float*)(ws + (7u  << 20));             // 4 MB
  float* x1      = (float*)(ws + (11u << 20));             // 4 MB
  u16*   gb      = (u16*)(ws + (15u << 20));               // 2 MB
  u16*   qbuf    = (u16*)(ws + (17u << 20));               // 2 MB
  u16*   kbuf    = (u16*)(ws + (19u << 20));               // 2 MB
  u16*   vTb     = (u16*)(ws + (21u << 20));               // 2 MB [256][4096]
  u16*   ctxb    = (u16*)(ws + (23u << 20));               // 2 MB
  float* x2      = (float*)(ws + (25u << 20));             // 4 MB
  u16*   yb      = (u16*)(ws + (29u << 20));               // 2 MB
  u16*   hid     = (u16*)(ws + (31u << 20));               // 8 MB
  int*   eperm   = (int*)(ws + (39u << 20));               // 512 KB
  int*   dst_s   = (int*)(ws + (39u << 20) + (512u << 10));// 512 KB
  int*   src_s   = (int*)(ws + (40u << 20));               // 512 KB
  u16*   hb      = (u16*)(ws + (40u << 20) + (512u << 10));// 2 MB

  const size_t O_EW1 = 0, O_EW2 = 65536, O_UW1 = 131072, O_UW2 = 196608,
               O_QKV = 262144, O_WO = 458752, O_FW1 = 524288, O_FW2 = 786432;
  const float qscale = 0.17677669529663687f;  // 1/sqrt(32)

  hipMemsetAsync(agg, 0, (4u << 20) + (32u << 10), stream);

  WPtrs wp;
  wp.p[0] = e_w1; wp.p[1] = e_w2; wp.p[2] = u_w1; wp.p[3] = u_w2;
  wp.p[4] = wq;   wp.p[5] = wk;   wp.p[6] = wv;   wp.p[7] = wo;
  wp.p[8] = f_w1; wp.p[9] = f_w2;
  setup_kernel<<<1025, 256, 0, stream>>>(wp, WP, qscale, ei, deg, bq, bk, bv, qkvbias);
  scan_kernel<<<1, 1024, 0, stream>>>(deg, offs);
  mid_kernel<<<4608, 256, 0, stream>>>(ei, offs, cnt, eperm, dst_s, src_s,
                                       x, ln_local_g, ln_local_b, hf, hb);

  edge_kernel<<<N_EDGES / 128, 256, 0, stream>>>(hb, edge_attr, eperm, src_s, dst_s,
                                                 WP + O_EW1, e_b1, WP + O_EW2, e_b2, agg);

  update_kernel<<<N_NODES / 32, 256, 0, stream>>>(hf, agg, eps, x,
                                                  WP + O_UW1, u_b1, WP + O_UW2, u_b2,
                                                  ln_global_g, ln_global_b, x1, gb);

  gemm_kernel<64, false, false, true, false, true><<<dim3(64, 3), 256, 0, stream>>>(
      gb, 256, WP + O_QKV, 256, 768, qkvbias, 1.0f, nullptr, nullptr, nullptr,
      nullptr, qbuf, kbuf, vTb, 256);

  attn_kernel<<<dim3(128, 8), 256, 0, stream>>>(qbuf, kbuf, vTb, ctxb);

  gemm_kernel<32, false, true, false, true, false><<<dim3(128, 1), 256, 0, stream>>>(
      ctxb, 256, WP + O_WO, 256, 256, bo, 1.0f, x1, ln_ffn_g, ln_ffn_b, x2, yb,
      nullptr, nullptr, 256);

  gemm_kernel<64, true, false, true, false, false><<<dim3(64, 4), 256, 0, stream>>>(
      yb, 256, WP + O_FW1, 256, 1024, f_b1, 1.0f, nullptr, nullptr, nullptr,
      nullptr, hid, nullptr, nullptr, 1024);

  gemm_kernel<32, false, true, false, false, false><<<dim3(128, 1), 256, 0, stream>>>(
      hid, 1024, WP + O_FW2, 1024, 256, f_b2, 1.0f, x2, nullptr, nullptr,
      (float*)d_out, nullptr, nullptr, nullptr, 256);
}